// Round 3
// baseline (218.446 us; speedup 1.0000x reference)
//
#include <hip/hip_runtime.h>
#include <math.h>

#define NPTS 2048
#define BLOCK 256
#define NW 4                    // waves per block
#define NB 2                    // batches per wave (sequential)
#define CHUNK_F 768             // floats per tensor per chunk (3 KB, 256 pts)
#define NCHUNK (NPTS * 3 / CHUNK_F)  // 8

// Direct-to-LDS, 16B/lane, wave-coalesced (lane i -> lds_base + 16*i).
#define GLD_LDS(gp, lp)                                                       \
  __builtin_amdgcn_global_load_lds(                                           \
      (const __attribute__((address_space(1))) void*)(gp),                    \
      (__attribute__((address_space(3))) void*)(lp), 16, 0, 0)

// One WAVE per batch element, 2 batches per wave. All global loads are
// lane-linear 1KB global_load_lds_dwordx4 (the 3 previous kernels all used
// stride-48B-per-lane loads -> ~48 cache lines touched per instruction ->
// TA/address-path saturated at ~80us regardless of structure). LDS is
// double-buffered per wave with counted vmcnt(6) so 6-12 KB/wave stays in
// flight; lanes then ds_read_b128 their contiguous 48B (stride-48 across
// lanes = conflict-free bank pattern for b128).
__global__ __launch_bounds__(BLOCK, 2) void kabsch_kernel(
    const float* __restrict__ P, const float* __restrict__ C,
    float* __restrict__ out, int B) {
  const int wave = threadIdx.x >> 6;
  const int lane = threadIdx.x & 63;

  __shared__ float lds[NW][2][2 * CHUNK_F];  // [wave][buf][P:768 | C:768] = 48 KB
  float* const buf0 = &lds[wave][0][0];
  float* const buf1 = &lds[wave][1][0];

  double rmsd_sum = 0.0;

#define ACCUM(PA, PB, PQ, CA, CB, CQ)                                   \
  do {                                                                  \
    const float Px[4] = {PA.x, PA.w, PB.z, PQ.y};                       \
    const float Py[4] = {PA.y, PB.x, PB.w, PQ.z};                       \
    const float Pz[4] = {PA.z, PB.y, PQ.x, PQ.w};                       \
    const float Cx[4] = {CA.x, CA.w, CB.z, CQ.y};                       \
    const float Cy[4] = {CA.y, CB.x, CB.w, CQ.z};                       \
    const float Cz[4] = {CA.z, CB.y, CQ.x, CQ.w};                       \
    _Pragma("unroll")                                                   \
    for (int i = 0; i < 4; i++) {                                       \
      const float px = Px[i], py = Py[i], pz = Pz[i];                   \
      const float cx = Cx[i], cy = Cy[i], cz = Cz[i];                   \
      acc[0] += px; acc[1] += py; acc[2] += pz;                         \
      acc[3] += cx; acc[4] += cy; acc[5] += cz;                         \
      acc[6] += px * px + py * py + pz * pz;                            \
      acc[7] += cx * cx + cy * cy + cz * cz;                            \
      acc[8]  += px * cx; acc[9]  += px * cy; acc[10] += px * cz;       \
      acc[11] += py * cx; acc[12] += py * cy; acc[13] += py * cz;       \
      acc[14] += pz * cx; acc[15] += pz * cy; acc[16] += pz * cz;       \
    }                                                                   \
  } while (0)

#define STAGE(dst, kk)                                                  \
  do {                                                                  \
    const float* ps = pB + (kk) * CHUNK_F + lane * 4;                   \
    const float* cs = cB + (kk) * CHUNK_F + lane * 4;                   \
    GLD_LDS(ps,       (dst));                                           \
    GLD_LDS(ps + 256, (dst) + 256);                                     \
    GLD_LDS(ps + 512, (dst) + 512);                                     \
    GLD_LDS(cs,       (dst) + 768);                                     \
    GLD_LDS(cs + 256, (dst) + 1024);                                    \
    GLD_LDS(cs + 512, (dst) + 1280);                                    \
  } while (0)

  for (int it = 0; it < NB; ++it) {
    const int b = (blockIdx.x * NW + wave) * NB + it;
    if (b < B) {
      const float* pB = P + (size_t)b * (NPTS * 3);
      const float* cB = C + (size_t)b * (NPTS * 3);

      float acc[17];
#pragma unroll
      for (int i = 0; i < 17; i++) acc[i] = 0.f;

      STAGE(buf0, 0);  // prologue: chunk 0 -> buf0 (6 loads in flight)
#pragma unroll
      for (int k = 0; k < NCHUNK; ++k) {
        float* const cur = (k & 1) ? buf1 : buf0;
        float* const nxt = (k & 1) ? buf0 : buf1;
        if (k + 1 < NCHUNK) {
          // prior iter's ds_reads of nxt retired before overwrite
          asm volatile("s_waitcnt lgkmcnt(0)" ::: "memory");
          STAGE(nxt, k + 1);  // 12 loads now outstanding
          asm volatile("s_waitcnt vmcnt(6)" ::: "memory");  // chunk k landed
        } else {
          asm volatile("s_waitcnt vmcnt(0)" ::: "memory");
        }
        __builtin_amdgcn_sched_barrier(0);
        const float4 pa = *(const float4*)(cur + 12 * lane);
        const float4 pb = *(const float4*)(cur + 12 * lane + 4);
        const float4 pq = *(const float4*)(cur + 12 * lane + 8);
        const float4 ca = *(const float4*)(cur + 768 + 12 * lane);
        const float4 cb = *(const float4*)(cur + 768 + 12 * lane + 4);
        const float4 cq = *(const float4*)(cur + 768 + 12 * lane + 8);
        ACCUM(pa, pb, pq, ca, cb, cq);
      }

      // wave (64-lane) butterfly reduce; lane 0 ends with the full sums
#pragma unroll
      for (int off = 32; off > 0; off >>= 1) {
#pragma unroll
        for (int i = 0; i < 17; i++) acc[i] += __shfl_down(acc[i], off);
      }

      if (lane == 0) {
        double s[17];
#pragma unroll
        for (int i = 0; i < 17; i++) s[i] = (double)acc[i];
        const double invN = 1.0 / (double)NPTS;
        const double spx = s[0], spy = s[1], spz = s[2];
        const double scx = s[3], scy = s[4], scz = s[5];
        const double Ep = s[6] - (spx * spx + spy * spy + spz * spz) * invN;
        const double Ec = s[7] - (scx * scx + scy * scy + scz * scz) * invN;
        const double a00 = s[8]  - spx * scx * invN, a01 = s[9]  - spx * scy * invN, a02 = s[10] - spx * scz * invN;
        const double a10 = s[11] - spy * scx * invN, a11 = s[12] - spy * scy * invN, a12 = s[13] - spy * scz * invN;
        const double a20 = s[14] - spz * scx * invN, a21 = s[15] - spz * scy * invN, a22 = s[16] - spz * scz * invN;
        const double det = a00 * (a11 * a22 - a12 * a21)
                         - a01 * (a10 * a22 - a12 * a20)
                         + a02 * (a10 * a21 - a11 * a20);
        const double b00 = a00 * a00 + a10 * a10 + a20 * a20;
        const double b11 = a01 * a01 + a11 * a11 + a21 * a21;
        const double b22 = a02 * a02 + a12 * a12 + a22 * a22;
        const double b01 = a00 * a01 + a10 * a11 + a20 * a21;
        const double b02 = a00 * a02 + a10 * a12 + a20 * a22;
        const double b12 = a01 * a02 + a11 * a12 + a21 * a22;
        const double q = (b00 + b11 + b22) / 3.0;
        const double p1 = b01 * b01 + b02 * b02 + b12 * b12;
        const double d0 = b00 - q, d1 = b11 - q, d2 = b22 - q;
        const double p2 = d0 * d0 + d1 * d1 + d2 * d2 + 2.0 * p1;
        double e1, e2, e3;
        if (p2 < 1e-30) {
          e1 = e2 = e3 = q;
        } else {
          const double pp = sqrt(p2 / 6.0);
          const double inv = 1.0 / pp;
          const double c00 = d0 * inv, c11 = d1 * inv, c22 = d2 * inv;
          const double c01 = b01 * inv, c02 = b02 * inv, c12 = b12 * inv;
          double r = 0.5 * (c00 * (c11 * c22 - c12 * c12)
                          - c01 * (c01 * c22 - c12 * c02)
                          + c02 * (c01 * c12 - c11 * c02));
          r = fmin(1.0, fmax(-1.0, r));
          const double phi = acos(r) / 3.0;
          e1 = q + 2.0 * pp * cos(phi);
          e3 = q + 2.0 * pp * cos(phi + 2.0943951023931953);  // smallest
          e2 = 3.0 * q - e1 - e3;
        }
        const double s1 = sqrt(fmax(e1, 0.0));
        const double s2 = sqrt(fmax(e2, 0.0));
        const double s3 = sqrt(fmax(e3, 0.0));
        const double dsign = (det > 0.0) ? 1.0 : ((det < 0.0) ? -1.0 : 0.0);
        const double trRS = s1 + s2 + dsign * s3;  // tr(R A^T)
        const double msd = (Ep + Ec - 2.0 * trRS) * invN;
        rmsd_sum += sqrt(fmax(msd, 0.0));
      }
    }
  }

  // combine the 4 per-wave sums -> one atomic per block
  __shared__ double red[NW];
  if (lane == 0) red[wave] = rmsd_sum;
  __syncthreads();
  if (threadIdx.x == 0) {
    const double sum = red[0] + red[1] + red[2] + red[3];
    atomicAdd(out, (float)(sum / (double)B));
  }
}

extern "C" void kernel_launch(void* const* d_in, const int* in_sizes, int n_in,
                              void* d_out, int out_size, void* d_ws, size_t ws_size,
                              hipStream_t stream) {
  const float* P = (const float*)d_in[0];
  const float* C = (const float*)d_in[1];
  float* out = (float*)d_out;
  const int B = in_sizes[0] / (NPTS * 3);
  hipMemsetAsync(out, 0, sizeof(float), stream);  // d_out poisoned before every call
  kabsch_kernel<<<(B + NW * NB - 1) / (NW * NB), BLOCK, 0, stream>>>(P, C, out, B);
}